// Round 15
// baseline (100.909 us; speedup 1.0000x reference)
//
#include <hip/hip_runtime.h>

// Problem constants: B=16, NEG=128, S=128, D=512, N_PRED=12
#define DIM 512
#define M_ROWS 2048      // B*S

typedef __attribute__((ext_vector_type(8))) short short8;   // 8 bf16 (4 VGPRs)
typedef __attribute__((ext_vector_type(4))) float f32x4;

// f32 -> bf16 round-to-nearest-even (inputs are well-scaled, no NaN expected)
static __device__ __forceinline__ short f2bf(float x) {
    unsigned int u = __builtin_bit_cast(unsigned int, x);
    u += 0x7fffu + ((u >> 16) & 1u);
    return (short)(u >> 16);
}

// ---------------- Kernel 1: c_proj = c @ W[k]^T + b[k], bf16 MFMA ----------------
// (unchanged from R3 — ~5 us, verified)
#define K1_PAD 40
__global__ __launch_bounds__(256) void cproj_mfma(
    const float* __restrict__ c, const float* __restrict__ W,
    const float* __restrict__ bias, const int* __restrict__ kptr,
    float* __restrict__ cp) {
    const int ksel = kptr[0];
    const float* __restrict__ Wk = W + (size_t)ksel * DIM * DIM;
    const float* __restrict__ bk = bias + (size_t)ksel * DIM;

    __shared__ short Alds[64][K1_PAD];
    __shared__ short Blds[64][K1_PAD];

    const int bm = blockIdx.x & 31;
    const int bn = blockIdx.x >> 5;
    const int t  = threadIdx.x;
    const int lane = t & 63;
    const int wv   = t >> 6;

    const int srow = t >> 2;
    const int sk   = (t & 3) * 8;

    const float* Ap = c  + (size_t)(bm * 64 + srow) * DIM + sk;
    const float* Bp = Wk + (size_t)(bn * 64 + srow) * DIM + sk;

    float4 a0 = *(const float4*)Ap,       a1 = *(const float4*)(Ap + 4);
    float4 b0 = *(const float4*)Bp,       b1 = *(const float4*)(Bp + 4);

    f32x4 acc[4] = {};

    const int frow = lane & 15;
    const int fk   = (lane >> 4) * 8;

    for (int step = 0; step < 16; ++step) {
        __syncthreads();
        short8 av, bv;
        av[0] = f2bf(a0.x); av[1] = f2bf(a0.y); av[2] = f2bf(a0.z); av[3] = f2bf(a0.w);
        av[4] = f2bf(a1.x); av[5] = f2bf(a1.y); av[6] = f2bf(a1.z); av[7] = f2bf(a1.w);
        bv[0] = f2bf(b0.x); bv[1] = f2bf(b0.y); bv[2] = f2bf(b0.z); bv[3] = f2bf(b0.w);
        bv[4] = f2bf(b1.x); bv[5] = f2bf(b1.y); bv[6] = f2bf(b1.z); bv[7] = f2bf(b1.w);
        *(short8*)&Alds[srow][sk] = av;
        *(short8*)&Blds[srow][sk] = bv;
        __syncthreads();
        if (step < 15) {
            const int off = (step + 1) * 32;
            a0 = *(const float4*)(Ap + off); a1 = *(const float4*)(Ap + off + 4);
            b0 = *(const float4*)(Bp + off); b1 = *(const float4*)(Bp + off + 4);
        }
        const short8 bfrag = *(const short8*)&Blds[wv * 16 + frow][fk];
#pragma unroll
        for (int f = 0; f < 4; ++f) {
            const short8 afrag = *(const short8*)&Alds[f * 16 + frow][fk];
            acc[f] = __builtin_amdgcn_mfma_f32_16x16x32_bf16(afrag, bfrag, acc[f], 0, 0, 0);
        }
    }

    const int col = bn * 64 + wv * 16 + frow;
    const float bias_v = bk[col];
    const int r0 = (lane >> 4) * 4;
#pragma unroll
    for (int f = 0; f < 4; ++f)
#pragma unroll
        for (int r = 0; r < 4; ++r)
            cp[(size_t)(bm * 64 + f * 16 + r0 + r) * DIM + col] = acc[f][r] + bias_v;
}

// ---------------- Kernel 2: out[b,n,s] = (1/512) * dot(cp[b,s,:], z[b,n,s,:]) ----
// R13 nt one-shot structure with slot depth 4 -> 8: each wave owns 8 n's, all
// 16 z loads (16 KB) issued non-temporally at wave birth. Halves cp-load and
// block-launch overhead (grid 8192); in-flight bytes/CU rises ~256->320 KB
// even at the lower occupancy (~90 VGPR -> ~20 waves/CU).
#define NS ((size_t)128 * 512)         // n-stride in z (floats)
#define LD4(p)   (*(const f32x4*)(p))
#define LD4NT(p) (__builtin_nontemporal_load((const f32x4*)(p)))

__global__ __launch_bounds__(256) void dot_kernel(
    const float* __restrict__ z, const float* __restrict__ cp,
    float* __restrict__ out) {
    const int blk  = blockIdx.x;             // 0..8191
    const int bs   = blk >> 2;               // b*128 + s (0..2047)
    const int nq   = blk & 3;                // n-group of 32
    const int wave = threadIdx.x >> 6;       // 0..3
    const int lane = threadIdx.x & 63;
    const int b = bs >> 7;
    const int s = bs & 127;

    // cp row -> registers, contiguous 1 KB halves (temporal: reused across blocks)
    const float* cpr = cp + (size_t)bs * DIM + lane * 4;
    const f32x4 c0 = LD4(cpr);
    const f32x4 c1 = LD4(cpr + 256);

    // wave's 8 n's: n = nq*32 + wave*8 + i, i = 0..7
    const int nbase = nq * 32 + wave * 8;
    const float* zp = z + (((size_t)(b * 128 + nbase)) * 128 + s) * DIM + lane * 4;
    float* outp = out + ((size_t)(b * 128 + nbase)) * 128 + s;

    // prologue: all 8 slots issued non-temporally (16 z + 2 cp loads in flight)
    const f32x4 zA0 = LD4NT(zp + 0 * NS), zA1 = LD4NT(zp + 0 * NS + 256);
    const f32x4 zB0 = LD4NT(zp + 1 * NS), zB1 = LD4NT(zp + 1 * NS + 256);
    const f32x4 zC0 = LD4NT(zp + 2 * NS), zC1 = LD4NT(zp + 2 * NS + 256);
    const f32x4 zD0 = LD4NT(zp + 3 * NS), zD1 = LD4NT(zp + 3 * NS + 256);
    const f32x4 zE0 = LD4NT(zp + 4 * NS), zE1 = LD4NT(zp + 4 * NS + 256);
    const f32x4 zF0 = LD4NT(zp + 5 * NS), zF1 = LD4NT(zp + 5 * NS + 256);
    const f32x4 zG0 = LD4NT(zp + 6 * NS), zG1 = LD4NT(zp + 6 * NS + 256);
    const f32x4 zH0 = LD4NT(zp + 7 * NS), zH1 = LD4NT(zp + 7 * NS + 256);

#define SLOT(Z0, Z1, II)                                                      \
    {                                                                          \
        float acc = Z0[0] * c0[0];                                             \
        acc = fmaf(Z0[1], c0[1], acc);                                         \
        acc = fmaf(Z0[2], c0[2], acc);                                         \
        acc = fmaf(Z0[3], c0[3], acc);                                         \
        acc = fmaf(Z1[0], c1[0], acc);                                         \
        acc = fmaf(Z1[1], c1[1], acc);                                         \
        acc = fmaf(Z1[2], c1[2], acc);                                         \
        acc = fmaf(Z1[3], c1[3], acc);                                         \
        _Pragma("unroll")                                                      \
        for (int off = 32; off; off >>= 1) acc += __shfl_xor(acc, off);        \
        if (lane == 0) outp[(size_t)(II) * 128] = acc * (1.0f / 512.0f);       \
    }

    SLOT(zA0, zA1, 0)
    SLOT(zB0, zB1, 1)
    SLOT(zC0, zC1, 2)
    SLOT(zD0, zD1, 3)
    SLOT(zE0, zE1, 4)
    SLOT(zF0, zF1, 5)
    SLOT(zG0, zG1, 6)
    SLOT(zH0, zH1, 7)
#undef SLOT
}

extern "C" void kernel_launch(void* const* d_in, const int* in_sizes, int n_in,
                              void* d_out, int out_size, void* d_ws, size_t ws_size,
                              hipStream_t stream) {
    const float* c    = (const float*)d_in[0];
    const float* z    = (const float*)d_in[1];
    const float* W    = (const float*)d_in[2];
    const float* bias = (const float*)d_in[3];
    const int*   kptr = (const int*)d_in[4];
    float* out = (float*)d_out;
    float* cp  = (float*)d_ws;   // 2048*512*4 = 4 MB scratch for c_proj

    // Kernel 1: 32 M-tiles x 8 N-tiles = 256 blocks, bf16 MFMA
    cproj_mfma<<<dim3(256), dim3(256), 0, stream>>>(c, W, bias, kptr, cp);
    // Kernel 2: 8192 one-shot blocks, 8 nt slots per wave
    dot_kernel<<<dim3(8192), dim3(256), 0, stream>>>(z, cp, out);
}

// Round 16
// 99.315 us; speedup vs baseline: 1.0161x; 1.0161x over previous
//
#include <hip/hip_runtime.h>

// Problem constants: B=16, NEG=128, S=128, D=512, N_PRED=12
#define DIM 512
#define M_ROWS 2048      // B*S

typedef __attribute__((ext_vector_type(8))) short short8;   // 8 bf16 (4 VGPRs)
typedef __attribute__((ext_vector_type(4))) float f32x4;

// f32 -> bf16 round-to-nearest-even (inputs are well-scaled, no NaN expected)
static __device__ __forceinline__ short f2bf(float x) {
    unsigned int u = __builtin_bit_cast(unsigned int, x);
    u += 0x7fffu + ((u >> 16) & 1u);
    return (short)(u >> 16);
}

// ---------------- Kernel 1: c_proj = c @ W[k]^T + b[k], bf16 MFMA ----------------
// (unchanged from R3 — ~5 us, verified)
#define K1_PAD 40
__global__ __launch_bounds__(256) void cproj_mfma(
    const float* __restrict__ c, const float* __restrict__ W,
    const float* __restrict__ bias, const int* __restrict__ kptr,
    float* __restrict__ cp) {
    const int ksel = kptr[0];
    const float* __restrict__ Wk = W + (size_t)ksel * DIM * DIM;
    const float* __restrict__ bk = bias + (size_t)ksel * DIM;

    __shared__ short Alds[64][K1_PAD];
    __shared__ short Blds[64][K1_PAD];

    const int bm = blockIdx.x & 31;
    const int bn = blockIdx.x >> 5;
    const int t  = threadIdx.x;
    const int lane = t & 63;
    const int wv   = t >> 6;

    const int srow = t >> 2;
    const int sk   = (t & 3) * 8;

    const float* Ap = c  + (size_t)(bm * 64 + srow) * DIM + sk;
    const float* Bp = Wk + (size_t)(bn * 64 + srow) * DIM + sk;

    float4 a0 = *(const float4*)Ap,       a1 = *(const float4*)(Ap + 4);
    float4 b0 = *(const float4*)Bp,       b1 = *(const float4*)(Bp + 4);

    f32x4 acc[4] = {};

    const int frow = lane & 15;
    const int fk   = (lane >> 4) * 8;

    for (int step = 0; step < 16; ++step) {
        __syncthreads();
        short8 av, bv;
        av[0] = f2bf(a0.x); av[1] = f2bf(a0.y); av[2] = f2bf(a0.z); av[3] = f2bf(a0.w);
        av[4] = f2bf(a1.x); av[5] = f2bf(a1.y); av[6] = f2bf(a1.z); av[7] = f2bf(a1.w);
        bv[0] = f2bf(b0.x); bv[1] = f2bf(b0.y); bv[2] = f2bf(b0.z); bv[3] = f2bf(b0.w);
        bv[4] = f2bf(b1.x); bv[5] = f2bf(b1.y); bv[6] = f2bf(b1.z); bv[7] = f2bf(b1.w);
        *(short8*)&Alds[srow][sk] = av;
        *(short8*)&Blds[srow][sk] = bv;
        __syncthreads();
        if (step < 15) {
            const int off = (step + 1) * 32;
            a0 = *(const float4*)(Ap + off); a1 = *(const float4*)(Ap + off + 4);
            b0 = *(const float4*)(Bp + off); b1 = *(const float4*)(Bp + off + 4);
        }
        const short8 bfrag = *(const short8*)&Blds[wv * 16 + frow][fk];
#pragma unroll
        for (int f = 0; f < 4; ++f) {
            const short8 afrag = *(const short8*)&Alds[f * 16 + frow][fk];
            acc[f] = __builtin_amdgcn_mfma_f32_16x16x32_bf16(afrag, bfrag, acc[f], 0, 0, 0);
        }
    }

    const int col = bn * 64 + wv * 16 + frow;
    const float bias_v = bk[col];
    const int r0 = (lane >> 4) * 4;
#pragma unroll
    for (int f = 0; f < 4; ++f)
#pragma unroll
        for (int r = 0; r < 4; ++r)
            cp[(size_t)(bm * 64 + f * 16 + r0 + r) * DIM + col] = acc[f][r] + bias_v;
}

// ---------------- Kernel 2: out[b,n,s] = (1/512) * dot(cp[b,s,:], z[b,n,s,:]) ----
// R13 nt one-shot 4-slot structure with ONE change: SINGLE-WAVE BLOCKS
// (64 threads, grid 65536). Waves were already independent (no syncthreads);
// 1-wave blocks release CU slots per-wave instead of per-4-wave-block, so the
// dispatcher backfills fresh waves (whose prologue loads sustain the in-flight
// pool) without waiting on a block's slowest straggler.
#define NS ((size_t)128 * 512)         // n-stride in z (floats)
#define LD4(p)   (*(const f32x4*)(p))
#define LD4NT(p) (__builtin_nontemporal_load((const f32x4*)(p)))

__global__ __launch_bounds__(64) void dot_kernel(
    const float* __restrict__ z, const float* __restrict__ cp,
    float* __restrict__ out) {
    const int blk  = blockIdx.x;             // 0..65535 = (bs << 5) | nslot
    const int bs   = blk >> 5;               // b*128 + s (0..2047)
    const int nslot= blk & 31;               // n-group of 4
    const int lane = threadIdx.x;            // 0..63
    const int b = bs >> 7;
    const int s = bs & 127;

    // cp row -> registers, contiguous 1 KB halves (temporal: reused 32x)
    const float* cpr = cp + (size_t)bs * DIM + lane * 4;
    const f32x4 c0 = LD4(cpr);
    const f32x4 c1 = LD4(cpr + 256);

    // wave's 4 n's: n = nslot*4 + i, i = 0..3
    const int nbase = nslot * 4;
    const float* zp = z + (((size_t)(b * 128 + nbase)) * 128 + s) * DIM + lane * 4;
    float* outp = out + ((size_t)(b * 128 + nbase)) * 128 + s;

    // prologue: all 4 slots issued non-temporally (8 z + 2 cp loads in flight)
    const f32x4 zA0 = LD4NT(zp + 0 * NS), zA1 = LD4NT(zp + 0 * NS + 256);
    const f32x4 zB0 = LD4NT(zp + 1 * NS), zB1 = LD4NT(zp + 1 * NS + 256);
    const f32x4 zC0 = LD4NT(zp + 2 * NS), zC1 = LD4NT(zp + 2 * NS + 256);
    const f32x4 zD0 = LD4NT(zp + 3 * NS), zD1 = LD4NT(zp + 3 * NS + 256);

#define SLOT(Z0, Z1, II)                                                      \
    {                                                                          \
        float acc = Z0[0] * c0[0];                                             \
        acc = fmaf(Z0[1], c0[1], acc);                                         \
        acc = fmaf(Z0[2], c0[2], acc);                                         \
        acc = fmaf(Z0[3], c0[3], acc);                                         \
        acc = fmaf(Z1[0], c1[0], acc);                                         \
        acc = fmaf(Z1[1], c1[1], acc);                                         \
        acc = fmaf(Z1[2], c1[2], acc);                                         \
        acc = fmaf(Z1[3], c1[3], acc);                                         \
        _Pragma("unroll")                                                      \
        for (int off = 32; off; off >>= 1) acc += __shfl_xor(acc, off);        \
        if (lane == 0) outp[(size_t)(II) * 128] = acc * (1.0f / 512.0f);       \
    }

    SLOT(zA0, zA1, 0)
    SLOT(zB0, zB1, 1)
    SLOT(zC0, zC1, 2)
    SLOT(zD0, zD1, 3)
#undef SLOT
}

extern "C" void kernel_launch(void* const* d_in, const int* in_sizes, int n_in,
                              void* d_out, int out_size, void* d_ws, size_t ws_size,
                              hipStream_t stream) {
    const float* c    = (const float*)d_in[0];
    const float* z    = (const float*)d_in[1];
    const float* W    = (const float*)d_in[2];
    const float* bias = (const float*)d_in[3];
    const int*   kptr = (const int*)d_in[4];
    float* out = (float*)d_out;
    float* cp  = (float*)d_ws;   // 2048*512*4 = 4 MB scratch for c_proj

    // Kernel 1: 32 M-tiles x 8 N-tiles = 256 blocks, bf16 MFMA
    cproj_mfma<<<dim3(256), dim3(256), 0, stream>>>(c, W, bias, kptr, cp);
    // Kernel 2: 65536 single-wave one-shot blocks, nt z loads
    dot_kernel<<<dim3(65536), dim3(64), 0, stream>>>(z, cp, out);
}